// Round 1
// baseline (529.375 us; speedup 1.0000x reference)
//
#include <hip/hip_runtime.h>

// TokenCombiner: row-shuffling copy.
// For each output row r: j = max{k : out_off[k] <= r}; pos = r - out_off[j];
// if pos < out_splits[j]: out[r] = inp[clip(in_off[j]+pos)], else out[r] = outbuf[r].
//
// Memory-bound: 256 MiB read + 256 MiB write -> ~85us floor at 6.3 TB/s.
// One block per output row; float4 vectorized, fully coalesced.

__global__ __launch_bounds__(256) void TokenCombiner_70523363000736_kernel(
    const float4* __restrict__ inp,      // [in_rows, hidden4] as float4
    const float4* __restrict__ outbuf,   // [out_rows, hidden4] passthrough values
    const int*    __restrict__ in_so,    // [2, nsplits]: row0=splits, row1=in_off
    const int*    __restrict__ out_so,   // [2, nsplits]: row0=splits, row1=out_off
    float4*       __restrict__ out,      // [out_rows, hidden4]
    int nsplits, int hidden4, int in_rows)
{
    const int row = blockIdx.x;

    const int* out_splits = out_so;
    const int* out_off    = out_so + nsplits;
    const int* in_off     = in_so  + nsplits;

    // searchsorted(out_off, row, 'right') - 1, clipped to [0, nsplits-1].
    // nsplits is tiny (8); linear scan, block-uniform -> scalar pipe.
    int j = 0;
    #pragma unroll 8
    for (int k = 1; k < nsplits; ++k)
        if (out_off[k] <= row) j = k;

    const int  pos   = row - out_off[j];
    const bool valid = pos < out_splits[j];

    long src = (long)in_off[j] + (long)pos;
    if (src < 0) src = 0;
    if (src > (long)(in_rows - 1)) src = (long)(in_rows - 1);

    const float4* src_row = valid ? (inp + src * (long)hidden4)
                                  : (outbuf + (long)row * (long)hidden4);
    float4* dst_row = out + (long)row * (long)hidden4;

    // hidden4 = 1024 on this problem -> 4 float4 per thread, coalesced.
    for (int c = threadIdx.x; c < hidden4; c += blockDim.x)
        dst_row[c] = src_row[c];
}

extern "C" void kernel_launch(void* const* d_in, const int* in_sizes, int n_in,
                              void* d_out, int out_size, void* d_ws, size_t ws_size,
                              hipStream_t stream) {
    const float4* inp    = (const float4*)d_in[0];
    const float4* outbuf = (const float4*)d_in[1];
    const int*    in_so  = (const int*)d_in[2];
    const int*    out_so = (const int*)d_in[3];
    float4*       out    = (float4*)d_out;

    const int hidden   = 4096;                 // fixed by problem (HIDDEN)
    const int hidden4  = hidden / 4;
    const int nsplits  = in_sizes[2] / 2;      // [2, nsplits] stacked
    const int in_rows  = in_sizes[0] / hidden;
    const int out_rows = out_size   / hidden;

    TokenCombiner_70523363000736_kernel<<<out_rows, 256, 0, stream>>>(
        inp, outbuf, in_so, out_so, out, nsplits, hidden4, in_rows);
}